// Round 8
// baseline (169.414 us; speedup 1.0000x reference)
//
#include <hip/hip_runtime.h>
#include <hip/hip_bf16.h>
#include <cstdint>

// Problem constants
#define B_DIM 2048
#define H_DIM 1024
#define K_DIM 2048   // 2*H  (input | hidden)
#define N_DIM 4096   // 4*H  (gates, interleaved n' = 4*h + gate)

typedef unsigned short u16;
typedef __attribute__((ext_vector_type(8))) short bf16x8;
typedef __attribute__((ext_vector_type(8))) unsigned short u16x8;
typedef __attribute__((ext_vector_type(4))) float f32x4;

__device__ __forceinline__ u16 f2bf(float f) {
    unsigned int u = __float_as_uint(f);
    u += 0x7FFFu + ((u >> 16) & 1u);   // round-to-nearest-even
    return (u16)(u >> 16);
}

__device__ __forceinline__ float sigmoid_f(float x) {
    return 1.0f / (1.0f + __expf(-x));
}

// tanh via exp, saturating form (no inf/inf NaN at large |x|)
__device__ __forceinline__ float tanh_f(float x) {
    float e = __expf(2.0f * x);
    return 1.0f - 2.0f / (e + 1.0f);
}

// async global->LDS 16B per lane. LDS dest is wave-uniform base + lane*16.
__device__ __forceinline__ void async16(const u16* g, u16* l) {
    __builtin_amdgcn_global_load_lds(
        (const __attribute__((address_space(1))) unsigned int*)g,
        (__attribute__((address_space(3))) unsigned int*)l,
        16, 0, 0);
}

// Explicit s_waitcnt vmcnt(0) (lgkmcnt/expcnt masked off).
// gfx9 simm16: vmcnt[3:0]=bits3:0, expcnt=bits6:4, lgkmcnt=bits11:8,
// vmcnt[5:4]=bits15:14 -> vmcnt(0) only = 0x0F70.
// NEEDED because __syncthreads does NOT reliably drain vmcnt for
// global_load_lds issued far from the barrier (R4 failed correctness
// exactly this way; this is the fix that makes issue-early legal).
__device__ __forceinline__ void drain_vmem() {
    __builtin_amdgcn_s_waitcnt(0x0F70);
}

// ---------------------------------------------------------------------------
// Kernel 1: all packing in ONE launch.
// Region A (blocks 0..4095):        A = [input|hidden] bf16 2048x2048
// Region B (blocks 4096..8191):     Bt[n'][k], n' = 4h+g (f,i,o,c)
// Region bias (blocks 8192..8207):  bias_il[4h+g] = b_g[h]
// ---------------------------------------------------------------------------
__global__ __launch_bounds__(256) void pack_all(
    const float* __restrict__ input, const float* __restrict__ hidden,
    const float* __restrict__ w_f, const float* __restrict__ w_i,
    const float* __restrict__ w_o, const float* __restrict__ w_c,
    const float* __restrict__ u_f, const float* __restrict__ u_i,
    const float* __restrict__ u_o, const float* __restrict__ u_c,
    const float* __restrict__ b1, const float* __restrict__ b2,
    const float* __restrict__ b3, const float* __restrict__ b4,
    u16* __restrict__ A, u16* __restrict__ Bt, float* __restrict__ bias_il) {
    __shared__ float tile[32][65];
    const int blk = blockIdx.x;
    const int t = threadIdx.x;

    if (blk < 4096) {
        // ---- pack_A ----
        int idx = (blk * 256 + t) * 4;
        int m = idx >> 11;
        int k = idx & (K_DIM - 1);
        const float* src = (k < H_DIM) ? (input + (size_t)m * H_DIM + k)
                                       : (hidden + (size_t)m * H_DIM + (k - H_DIM));
        float4 v = *(const float4*)src;
        ushort4 o;
        o.x = f2bf(v.x); o.y = f2bf(v.y); o.z = f2bf(v.z); o.w = f2bf(v.w);
        *(ushort4*)(A + idx) = o;
    } else if (blk < 8192) {
        // ---- pack_B: 32h x 64k tile transpose ----
        int b2i = blk - 4096;
        int z = b2i >> 9;
        int rem = b2i & 511;
        int hx = rem & 31;
        int ky = rem >> 5;
        const float* M;
        switch (z) {
            case 0: M = w_f; break;
            case 1: M = w_i; break;
            case 2: M = w_o; break;
            case 3: M = w_c; break;
            case 4: M = u_f; break;
            case 5: M = u_i; break;
            case 6: M = u_o; break;
            default: M = u_c; break;
        }
        const int g = z & 3;
        const int half = z >> 2;
        const int h0 = hx * 32;
        const int k0 = ky * 64;
#pragma unroll
        for (int it = 0; it < 2; it++) {
            int kl = (t >> 3) + it * 32;
            int hl = (t & 7) * 4;
            float4 v = *(const float4*)(M + (size_t)(k0 + kl) * H_DIM + h0 + hl);
            tile[hl + 0][kl] = v.x;
            tile[hl + 1][kl] = v.y;
            tile[hl + 2][kl] = v.z;
            tile[hl + 3][kl] = v.w;
        }
        __syncthreads();
        int hl = t >> 3;
        int ko = (t & 7) * 8;
        u16x8 o;
#pragma unroll
        for (int q = 0; q < 8; q++) o[q] = f2bf(tile[hl][ko + q]);
        size_t n = 4 * (size_t)(h0 + hl) + g;
        *(u16x8*)(Bt + n * K_DIM + half * H_DIM + k0 + ko) = o;
    } else {
        // ---- pack_bias ----
        int idx = (blk - 8192) * 256 + t;
        int h = idx >> 2, g = idx & 3;
        const float* b = (g == 0) ? b1 : (g == 1) ? b2 : (g == 2) ? b3 : b4;
        bias_il[idx] = b[h];
    }
}

// ---------------------------------------------------------------------------
// Kernel 2: fused GEMM + LSTM epilogue.  BM=BN=128, BK=64 (R5's proven best
// tile: two 32-k slabs/operand, 16x16x32 MFMA, bank-balanced frag layout).
// NEW: true double-buffer. Two 32KB buffer sets; each set's loads are issued
// one full compute phase before the barrier that publishes them, and the
// publish barrier is preceded by an EXPLICIT s_waitcnt vmcnt(0) (drain_vmem).
// R4 proved __syncthreads alone does not drain distant global_load_lds
// (wrong results); with the explicit drain the early issue is legal and the
// ~900cyc L2 latency is covered by the other buffer's 32 MFMAs.
// ---------------------------------------------------------------------------
#define BM 128
#define BN 128
#define BK 64
#define SL (64 * 32)   // u16 elements per half-slab issue offset

__global__ __launch_bounds__(256, 2) void gemm_fused(
    const u16* __restrict__ A, const u16* __restrict__ Bt,
    const float* __restrict__ bias_il, const float* __restrict__ pre_cell,
    const float* __restrict__ mask, float* __restrict__ out) {
    __shared__ char smem[65536];
    // set0: AsL 0K, AsH 8K, BsL 16K, BsH 24K ; set1: +32K
    u16* A0L = (u16*)smem;
    u16* A0H = (u16*)(smem + 8192);
    u16* B0L = (u16*)(smem + 16384);
    u16* B0H = (u16*)(smem + 24576);
    u16* A1L = (u16*)(smem + 32768);
    u16* A1H = (u16*)(smem + 40960);
    u16* B1L = (u16*)(smem + 49152);
    u16* B1H = (u16*)(smem + 57344);
    float* et = (float*)smem;              // epilogue reuse: [128][33] f32

    const int t = threadIdx.x;
    const int w = t >> 6, l = t & 63;
    const int m0 = blockIdx.y * BM;
    const int n0 = blockIdx.x * BN;
    const int wr = w >> 1;    // wave row in 2x2
    const int wc = w & 1;     // wave col
    const int lrow = l & 15;
    const int quad = l >> 4;

    // staging: lane l of wave w covers row w*16+(l>>2) (+64 for 2nd issue),
    // k-offset (l&3)*8 within a 32-k slab. LDS addr = uniform base + 16*lane.
    const int sr = w * 16 + (l >> 2);
    const int sc = (l & 3) * 8;
    const u16* Ag0 = A + (size_t)(m0 + sr) * K_DIM + sc;
    const u16* Ag1 = Ag0 + (size_t)64 * K_DIM;
    const u16* Bg0 = Bt + (size_t)(n0 + sr) * K_DIM + sc;
    const u16* Bg1 = Bg0 + (size_t)64 * K_DIM;
    const int soff = sr * 32 + sc;

    const int foA = (wr * 64 + lrow) * 32 + quad * 8;
    const int foB = (wc * 64 + lrow) * 32 + quad * 8;

    // acc init = bias (constant down a column)
    f32x4 acc[4][4];
#pragma unroll
    for (int j = 0; j < 4; j++) {
        float bv = bias_il[n0 + wc * 64 + j * 16 + lrow];
#pragma unroll
        for (int i = 0; i < 4; i++) acc[i][j] = (f32x4){bv, bv, bv, bv};
    }

#define STAGE(AL, AH, BL, BH, koff)              \
    async16(Ag0 + (koff), AL + soff);            \
    async16(Ag1 + (koff), AL + soff + SL);       \
    async16(Ag0 + (koff) + 32, AH + soff);       \
    async16(Ag1 + (koff) + 32, AH + soff + SL);  \
    async16(Bg0 + (koff), BL + soff);            \
    async16(Bg1 + (koff), BL + soff + SL);       \
    async16(Bg0 + (koff) + 32, BH + soff);       \
    async16(Bg1 + (koff) + 32, BH + soff + SL);

#define COMPUTE(AL, AH, BL, BH)                                             \
    {                                                                       \
        _Pragma("unroll") for (int s = 0; s < 2; s++) {                     \
            const u16* Asb = s ? (AH) : (AL);                               \
            const u16* Bsb = s ? (BH) : (BL);                               \
            bf16x8 af[4], bf[4];                                            \
            _Pragma("unroll") for (int i = 0; i < 4; i++)                   \
                af[i] = *(const bf16x8*)(Asb + foA + i * 16 * 32);          \
            _Pragma("unroll") for (int j = 0; j < 4; j++)                   \
                bf[j] = *(const bf16x8*)(Bsb + foB + j * 16 * 32);          \
            _Pragma("unroll") for (int i = 0; i < 4; i++)                   \
                _Pragma("unroll") for (int j = 0; j < 4; j++)               \
                    acc[i][j] = __builtin_amdgcn_mfma_f32_16x16x32_bf16(    \
                        af[i], bf[j], acc[i][j], 0, 0, 0);                  \
        }                                                                   \
    }

    // prologue: prefetch k=0 into set0
    STAGE(A0L, A0H, B0L, B0H, 0);

    for (int k0 = 0; k0 < K_DIM; k0 += 2 * BK) {   // 16 iterations
        drain_vmem();                    // set0 loads done (issued early)
        __syncthreads();                 // publish set0; prior reads finished
        STAGE(A1L, A1H, B1L, B1H, k0 + BK);        // k0+BK <= 1984 always
        COMPUTE(A0L, A0H, B0L, B0H);     // 32 MFMAs cover set1's latency
        drain_vmem();                    // set1 loads done
        __syncthreads();                 // publish set1
        if (k0 + 2 * BK < K_DIM) {
            STAGE(A0L, A0H, B0L, B0H, k0 + 2 * BK);
        }
        COMPUTE(A1L, A1H, B1L, B1H);
    }
#undef STAGE
#undef COMPUTE

    // ---- fused LSTM epilogue ----
    // C/D layout: col = lane&15, row = quad*4 + reg  [m89/m91-verified]
    const int row = t >> 1;     // 0..127
    const int half = t & 1;     // 0 -> wc=0 cols, 1 -> wc=1 cols
    const size_t orow = (size_t)(m0 + row) * H_DIM;

    // prefetch epilogue operands now; latency hides under the 4 LDS phases
    float4 pc[4], mk[4];
#pragma unroll
    for (int j = 0; j < 4; j++) {
        const int hg0 = (n0 >> 2) + half * 16 + j * 4;
        pc[j] = *(const float4*)(pre_cell + orow + hg0);
        mk[j] = *(const float4*)(mask + orow + hg0);
    }

#pragma unroll
    for (int j = 0; j < 4; j++) {
        __syncthreads();        // et aliases set0; all prior reads complete
#pragma unroll
        for (int i = 0; i < 4; i++)
#pragma unroll
            for (int r = 0; r < 4; r++)
                et[(wr * 64 + i * 16 + quad * 4 + r) * 33 + wc * 16 + lrow] =
                    acc[i][j][r];
        __syncthreads();
        const int hg0 = (n0 >> 2) + half * 16 + j * 4;
        const float* ep = et + row * 33 + half * 16;  // 4h x 4gates = 16 f32
        const float* ppc = (const float*)&pc[j];
        const float* pmk = (const float*)&mk[j];
        float4 oh, oc;
        float* poh = (float*)&oh;
        float* poc = (float*)&oc;
#pragma unroll
        for (int q = 0; q < 4; q++) {
            float fv = sigmoid_f(ep[4 * q + 0]);
            float iv = sigmoid_f(ep[4 * q + 1]);
            float ov = sigmoid_f(ep[4 * q + 2]);
            float gv = tanh_f(ep[4 * q + 3]);
            float cv = ppc[q] * fv + iv * gv;
            poc[q] = cv;
            poh[q] = ov * tanh_f(cv) * pmk[q];
        }
        *(float4*)(out + orow + hg0) = oh;
        *(float4*)(out + (size_t)B_DIM * H_DIM + orow + hg0) = oc;
    }
}

// ---------------------------------------------------------------------------
extern "C" void kernel_launch(void* const* d_in, const int* in_sizes, int n_in,
                              void* d_out, int out_size, void* d_ws, size_t ws_size,
                              hipStream_t stream) {
    const float* input    = (const float*)d_in[0];
    const float* hidden   = (const float*)d_in[1];
    const float* pre_cell = (const float*)d_in[2];
    const float* w_i = (const float*)d_in[3];
    const float* w_f = (const float*)d_in[4];
    const float* w_o = (const float*)d_in[5];
    const float* w_c = (const float*)d_in[6];
    const float* u_i = (const float*)d_in[7];
    const float* u_f = (const float*)d_in[8];
    const float* u_o = (const float*)d_in[9];
    const float* u_c = (const float*)d_in[10];
    const float* b1  = (const float*)d_in[11];
    const float* b2  = (const float*)d_in[12];
    const float* b3  = (const float*)d_in[13];
    const float* b4  = (const float*)d_in[14];
    const float* mask = (const float*)d_in[15];
    float* out = (float*)d_out;

    // workspace: A bf16 (8 MiB) | Bt bf16 (16 MiB) | bias_il (16 KiB)
    char* ws = (char*)d_ws;
    u16*   A       = (u16*)ws;
    u16*   Bt      = (u16*)(ws + (size_t)8 * 1024 * 1024);
    float* bias_il = (float*)(ws + (size_t)24 * 1024 * 1024);

    pack_all<<<dim3(4096 + 4096 + 16), dim3(256), 0, stream>>>(
        input, hidden, w_f, w_i, w_o, w_c, u_f, u_i, u_o, u_c,
        b1, b2, b3, b4, A, Bt, bias_il);
    gemm_fused<<<dim3(N_DIM / BN, B_DIM / BM), dim3(256), 0, stream>>>(
        A, Bt, bias_il, pre_cell, mask, out);
}